// Round 17
// baseline (498.838 us; speedup 1.0000x reference)
//
#include <hip/hip_runtime.h>
#include <hip/hip_bf16.h>

#define HD  256
#define HD2 512
#define HD3 768
#define HD4 1024
#define NB  4096   // number of graphs (B)
#define NWAVES 16384
#define NBLK (NWAVES / 4)
#define RCHUNK 32
#define NCHUNK (NBLK / RCHUNK)

static __device__ __forceinline__ float lrelu(float x) { return x >= 0.f ? x : 0.01f * x; }
static __device__ __forceinline__ unsigned short rne_bf16(float f) {
  unsigned u = __float_as_uint(f);
  u += 0x7FFF + ((u >> 16) & 1);
  return (unsigned short)(u >> 16);
}
static __device__ __forceinline__ float b2f(unsigned short u) {
  return __uint_as_float((unsigned)u << 16);
}
static __device__ __forceinline__ void fma4(float4& acc, float a, ushort4 z) {
  acc.x = fmaf(a, b2f(z.x), acc.x);
  acc.y = fmaf(a, b2f(z.y), acc.y);
  acc.z = fmaf(a, b2f(z.z), acc.z);
  acc.w = fmaf(a, b2f(z.w), acc.w);
}

typedef short v8s __attribute__((ext_vector_type(8)));
typedef float v4f __attribute__((ext_vector_type(4)));

#define GLD16(gp, lp) __builtin_amdgcn_global_load_lds( \
    (const __attribute__((address_space(1))) void*)(gp), \
    (__attribute__((address_space(3))) void*)(lp), 16, 0, 0)

// ---------------- bf16 MFMA GEMM, 512 thr / 8 waves (2x4), block tile 128x256, BK=64.
// (R14-verified best: 107 us on the projection; single-buffer, 2 barriers/step.)
// Rows are 128B (8 segs of 16B). Seg s stored linearly; global kseg = (s&7)^((s>>3)&7);
// read col = ks^(r&7) (same involution; rule #21). C[M, Nout=gridDim.y*256] (+shift).
__global__ __launch_bounds__(512)
void gemm2(const unsigned short* __restrict__ A, int lda,
           const unsigned short* __restrict__ B, int ldb,
           const float* __restrict__ shiftv,
           float* __restrict__ C, unsigned short* __restrict__ Cb, int ldc,
           int M, int K)
{
  __shared__ unsigned short Asw[128 * 64];   // 16 KB
  __shared__ unsigned short Bsw[256 * 64];   // 32 KB
  const int tid = threadIdx.x;
  const int lane = tid & 63, w = tid >> 6;   // 8 waves
  const int bm = blockIdx.x * 128, bn = blockIdx.y * 256;
  const int wr = w >> 2, wc = w & 3;         // wave tile: rows wr*64, cols wc*64
  const int fr = lane & 15, fkseg = lane >> 4;
  v4f acc[4][4] = {};
  for (int k0 = 0; k0 < K; k0 += 64) {
    // stage A: 1024 segs (16B); 2 per thread; wave-uniform dest base + lane*16
    #pragma unroll
    for (int i = 0; i < 2; ++i) {
      const int s = i * 512 + w * 64 + lane;
      const int row = s >> 3;
      const int gk = (s & 7) ^ (row & 7);
      int gr = bm + row; gr = gr < M ? gr : M - 1;
      GLD16(A + (size_t)gr * lda + k0 + gk * 8, &Asw[(size_t)(i * 512 + w * 64) * 8]);
    }
    // stage B: 2048 segs; 4 per thread
    #pragma unroll
    for (int i = 0; i < 4; ++i) {
      const int s = i * 512 + w * 64 + lane;
      const int row = s >> 3;
      const int gk = (s & 7) ^ (row & 7);
      GLD16(B + (size_t)(bn + row) * ldb + k0 + gk * 8, &Bsw[(size_t)(i * 512 + w * 64) * 8]);
    }
    __syncthreads();
    #pragma unroll
    for (int kk = 0; kk < 2; ++kk) {
      v8s a[4], b[4];
      #pragma unroll
      for (int m = 0; m < 4; ++m) {
        const int r = wr * 64 + m * 16 + fr;
        const int ks = kk * 4 + fkseg;
        a[m] = *(const v8s*)&Asw[(size_t)(r * 8 + (ks ^ (r & 7))) * 8];
      }
      #pragma unroll
      for (int n = 0; n < 4; ++n) {
        const int r = wc * 64 + n * 16 + fr;
        const int ks = kk * 4 + fkseg;
        b[n] = *(const v8s*)&Bsw[(size_t)(r * 8 + (ks ^ (r & 7))) * 8];
      }
      #pragma unroll
      for (int m = 0; m < 4; ++m)
        #pragma unroll
        for (int n = 0; n < 4; ++n)
          acc[m][n] = __builtin_amdgcn_mfma_f32_16x16x32_bf16(a[m], b[n], acc[m][n], 0, 0, 0);
    }
    __syncthreads();
  }
  const int cr = (lane >> 4) * 4;  // C frag: row=(lane>>4)*4+r, col=lane&15 (m89-verified)
  const int cc = lane & 15;
  #pragma unroll
  for (int m = 0; m < 4; ++m) {
    #pragma unroll
    for (int r = 0; r < 4; ++r) {
      const int row = bm + wr * 64 + m * 16 + cr + r;
      if (row < M) {
        const int col = bn + wc * 64 + cc;
        #pragma unroll
        for (int n = 0; n < 4; ++n) {
          float v = acc[m][n][r];
          if (shiftv) v += shiftv[col + n * 16];
          if (Cb) Cb[(size_t)row * ldc + col + n * 16] = rne_bf16(v);
          else    C [(size_t)row * ldc + col + n * 16] = v;
        }
      }
    }
  }
}

// Wp[n,k] = bf16(Wout[n,k]*sc[k]);  shiftv[n] = bout[n] + sum_k sh[k]*Wout[n,k]
__global__ __launch_bounds__(256)
void fold_w(const float* __restrict__ Wout, int ldw,
            const float* __restrict__ sc, const float* __restrict__ sh,
            const float* __restrict__ bout,
            unsigned short* __restrict__ Wp, int ldp,
            float* __restrict__ shiftv, int K)
{
  const int n = blockIdx.x;
  const int t = threadIdx.x;
  float s = 0.f;
  for (int k = t; k < K; k += 256) {
    float wv = Wout[(size_t)n * ldw + k];
    s = fmaf(sh[k], wv, s);
    Wp[(size_t)n * ldp + k] = rne_bf16(wv * sc[k]);
  }
  __shared__ float red[256];
  red[t] = s; __syncthreads();
  for (int o = 128; o; o >>= 1) { if (t < o) red[t] += red[t + o]; __syncthreads(); }
  if (t == 0) shiftv[n] = red[0] + (bout ? bout[n] : 0.f);
}

__global__ void f2b_kernel(const float* __restrict__ src, unsigned short* __restrict__ dst, int n) {
  int i = blockIdx.x * 256 + threadIdx.x;
  if (i < n) dst[i] = rne_bf16(src[i]);
}

// fused 4-buffer fp32->bf16 (GRU weights)
__global__ void f2b4_kernel(const float* __restrict__ a, unsigned short* __restrict__ da, int na,
                            const float* __restrict__ b, unsigned short* __restrict__ db, int nb_,
                            const float* __restrict__ c, unsigned short* __restrict__ dc, int nc,
                            const float* __restrict__ d, unsigned short* __restrict__ dd, int nd) {
  int i = blockIdx.x * 256 + threadIdx.x;
  if (i < na) { da[i] = rne_bf16(a[i]); return; }
  i -= na;
  if (i < nb_) { db[i] = rne_bf16(b[i]); return; }
  i -= nb_;
  if (i < nc) { dc[i] = rne_bf16(c[i]); return; }
  i -= nc;
  if (i < nd) dd[i] = rne_bf16(d[i]);
}

// ---------------- generic fp32 GEMM (zemb only)
#define TS 64
#define KS 16
__global__ __launch_bounds__(256)
void gemm_tn(const float* __restrict__ A, int lda,
             const float* __restrict__ W, int ldw,
             float* __restrict__ C, int ldc,
             int M, int K)
{
  __shared__ float As[KS][TS + 1];
  __shared__ float Ws[KS][TS + 1];
  const int tid = threadIdx.x;
  const int bm = blockIdx.x * TS;
  const int bn = blockIdx.y * TS;
  const int r  = tid >> 2;
  const int kc = (tid & 3) << 2;
  const int tm = (tid >> 4) << 2;
  const int tn = (tid & 15) << 2;
  float acc[4][4] = {};
  for (int k0 = 0; k0 < K; k0 += KS) {
    float4 av = make_float4(0.f, 0.f, 0.f, 0.f);
    const int row = bm + r;
    if (row < M) av = *(const float4*)(A + (size_t)row * lda + k0 + kc);
    As[kc + 0][r] = av.x; As[kc + 1][r] = av.y; As[kc + 2][r] = av.z; As[kc + 3][r] = av.w;
    float4 wv = *(const float4*)(W + (size_t)(bn + r) * ldw + k0 + kc);
    Ws[kc + 0][r] = wv.x; Ws[kc + 1][r] = wv.y; Ws[kc + 2][r] = wv.z; Ws[kc + 3][r] = wv.w;
    __syncthreads();
    #pragma unroll
    for (int kk = 0; kk < KS; ++kk) {
      float a_[4], b_[4];
      #pragma unroll
      for (int i = 0; i < 4; ++i) a_[i] = As[kk][tm + i];
      #pragma unroll
      for (int j = 0; j < 4; ++j) b_[j] = Ws[kk][tn + j];
      #pragma unroll
      for (int i = 0; i < 4; ++i)
        #pragma unroll
        for (int j = 0; j < 4; ++j) acc[i][j] = fmaf(a_[i], b_[j], acc[i][j]);
    }
    __syncthreads();
  }
  #pragma unroll
  for (int i = 0; i < 4; ++i) {
    const int row = bm + tm + i;
    if (row < M)
      *(float4*)(C + (size_t)row * ldc + bn + tn) =
          make_float4(acc[i][0], acc[i][1], acc[i][2], acc[i][3]);
  }
}

// per-vocab attention scalars
__global__ __launch_bounds__(256)
void psv_kernel(const float* __restrict__ zemb, const float* __restrict__ as_,
                const float* __restrict__ ad_, float* __restrict__ psv,
                float* __restrict__ pdv, int V)
{
  int v = (int)((blockIdx.x * 256u + threadIdx.x) >> 6);
  int l = blockIdx.y;
  int lane = threadIdx.x & 63;
  if (v >= V) return;
  float4 zv = ((const float4*)(zemb + (size_t)v * HD4 + (size_t)l * HD))[lane];
  float4 a  = ((const float4*)(as_ + (size_t)l * HD))[lane];
  float4 b  = ((const float4*)(ad_ + (size_t)l * HD))[lane];
  float s = zv.x * a.x + zv.y * a.y + zv.z * a.z + zv.w * a.w;
  float d = zv.x * b.x + zv.y * b.y + zv.z * b.z + zv.w * b.w;
  #pragma unroll
  for (int o = 32; o; o >>= 1) { s += __shfl_down(s, o); d += __shfl_down(d, o); }
  if (lane == 0) { psv[(size_t)l * V + v] = s; pdv[(size_t)l * V + v] = d; }
}

// ---------------- CSR build (by dst) ----------------
__global__ void deg_hist(const int* __restrict__ dst, int* __restrict__ deg, int E) {
  int e = blockIdx.x * 256 + threadIdx.x;
  if (e < E) atomicAdd(&deg[dst[e]], 1);
}

#define SCB 1024
__global__ void scan_bsum(const int* __restrict__ deg, int* __restrict__ bsum, int N) {
  __shared__ int sh[256];
  int base = blockIdx.x * SCB;
  int t = threadIdx.x;
  int s = 0;
  for (int i = t; i < SCB; i += 256) { int idx = base + i; s += (idx < N) ? deg[idx] : 0; }
  sh[t] = s; __syncthreads();
  for (int o = 128; o; o >>= 1) { if (t < o) sh[t] += sh[t + o]; __syncthreads(); }
  if (t == 0) bsum[blockIdx.x] = sh[0];
}
__global__ void scan_small(int* __restrict__ bsum, int nb) {
  if (threadIdx.x == 0) {
    int acc = 0;
    for (int i = 0; i < nb; ++i) { int v = bsum[i]; bsum[i] = acc; acc += v; }
  }
}
__global__ void scan_final(const int* __restrict__ deg, const int* __restrict__ bsum,
                           int* __restrict__ rowptr, int N, int E) {
  __shared__ int sh[256];
  int base = blockIdx.x * SCB;
  int t = threadIdx.x;
  int idx0 = base + t * 4;
  int v[4]; int s = 0;
  #pragma unroll
  for (int j = 0; j < 4; ++j) { int idx = idx0 + j; v[j] = (idx < N) ? deg[idx] : 0; s += v[j]; }
  sh[t] = s; __syncthreads();
  for (int o = 1; o < 256; o <<= 1) {
    int x = (t >= o) ? sh[t - o] : 0;
    __syncthreads();
    sh[t] += x;
    __syncthreads();
  }
  int off = bsum[blockIdx.x] + ((t == 0) ? 0 : sh[t - 1]);
  #pragma unroll
  for (int j = 0; j < 4; ++j) {
    int idx = idx0 + j;
    if (idx < N) rowptr[idx] = off;
    off += v[j];
  }
  if (idx0 <= N - 1 && N - 1 < idx0 + 4) rowptr[N] = E;
}
__global__ void scatter_edges(const int* __restrict__ src, const int* __restrict__ dst,
                              const int* __restrict__ wid, int* __restrict__ cursor,
                              int* __restrict__ swids, int* __restrict__ dwids, int E) {
  int e = blockIdx.x * 256 + threadIdx.x;
  if (e >= E) return;
  int pos = atomicAdd(&cursor[dst[e]], 1);
  swids[pos] = wid[src[e]];
  dwids[pos] = wid[dst[e]];
}

// edge-balanced strip boundaries
__global__ void balance_strips(const int* __restrict__ rowptr, int* __restrict__ wstart,
                               int N, int E, int NW) {
  int w = blockIdx.x * 256 + threadIdx.x;
  if (w > NW) return;
  if (w == 0)  { wstart[0] = 0; return; }
  if (w == NW) { wstart[NW] = N; return; }
  long long target = (long long)E * w / NW;
  int lo = 0, hi = N;
  while (lo < hi) {
    int mid = (lo + hi + 1) >> 1;
    if ((long long)rowptr[mid] <= target) lo = mid; else hi = mid - 1;
  }
  wstart[w] = lo;
}

// graph rowptr from sorted n2g
__global__ void grow_fill(const int* __restrict__ n2g, int* __restrict__ grow, int N, int B) {
  int n = blockIdx.x * 256 + threadIdx.x;
  if (n > N) return;
  int prev = (n == 0) ? -1 : n2g[n - 1];
  int cur  = (n == N) ? B  : n2g[n];
  for (int g = prev + 1; g <= cur && g <= B; ++g) grow[g] = n;
}

// block-per-graph mean (sorted segments, no atomics), bf16 output
__global__ __launch_bounds__(256)
void seg_mean(const float* __restrict__ X, const int* __restrict__ gather,
              const int* __restrict__ grow, unsigned short* __restrict__ outb)
{
  int g = blockIdx.x, h = threadIdx.x;
  int n0 = grow[g], n1 = grow[g + 1];
  float s = 0.f;
  for (int n = n0; n < n1; ++n) {
    int row = gather ? gather[n] : n;
    s += X[(size_t)row * HD + h];
  }
  outb[(size_t)g * HD + h] = rne_bf16(s / fmaxf((float)(n1 - n0), 1.f));
}

// per-edge scores for all 4 layers
__global__ void edge_score(const int* __restrict__ swids, const int* __restrict__ dwids,
                           const float* __restrict__ psv, const float* __restrict__ pdv,
                           float4* __restrict__ es4, int E, int V) {
  int i = blockIdx.x * 256 + threadIdx.x;
  if (i >= E) return;
  int sw = swids[i], dw = dwids[i];
  float4 e;
  e.x = lrelu(psv[0 * V + sw] + pdv[0 * V + dw]);
  e.y = lrelu(psv[1 * V + sw] + pdv[1 * V + dw]);
  e.z = lrelu(psv[2 * V + sw] + pdv[2 * V + dw]);
  e.w = lrelu(psv[3 * V + sw] + pdv[3 * V + dw]);
  es4[i] = e;
}

// per-node scalar softmax: overwrite es4 with normalized alpha
__global__ __launch_bounds__(256)
void alpha_node(const int* __restrict__ rowptr, float4* __restrict__ es4, int N) {
  int n = blockIdx.x * 256 + threadIdx.x;
  if (n >= N) return;
  int b0 = rowptr[n], b1 = rowptr[n + 1];
  if (b0 == b1) return;
  float4 m = make_float4(-INFINITY, -INFINITY, -INFINITY, -INFINITY);
  for (int i = b0; i < b1; ++i) {
    float4 e = es4[i];
    m.x = fmaxf(m.x, e.x); m.y = fmaxf(m.y, e.y);
    m.z = fmaxf(m.z, e.z); m.w = fmaxf(m.w, e.w);
  }
  float4 s = make_float4(0.f, 0.f, 0.f, 0.f);
  for (int i = b0; i < b1; ++i) {
    float4 e = es4[i];
    e.x = expf(e.x - m.x); e.y = expf(e.y - m.y);
    e.z = expf(e.z - m.z); e.w = expf(e.w - m.w);
    s.x += e.x; s.y += e.y; s.z += e.z; s.w += e.w;
    es4[i] = e;
  }
  float4 inv;
  inv.x = 1.f / (s.x == 0.f ? 1.f : s.x);
  inv.y = 1.f / (s.y == 0.f ? 1.f : s.y);
  inv.z = 1.f / (s.z == 0.f ? 1.f : s.z);
  inv.w = 1.f / (s.w == 0.f ? 1.f : s.w);
  for (int i = b0; i < b1; ++i) {
    float4 e = es4[i];
    e.x *= inv.x; e.y *= inv.y; e.z *= inv.z; e.w *= inv.w;
    es4[i] = e;
  }
}

// ---------------- edge-balanced strip aggregation; per-block BN partials (NO global atomics)
__global__ __launch_bounds__(256)
void gat_strip(const int* __restrict__ rowptr, const int* __restrict__ wstart,
               const int* __restrict__ swids, const float4* __restrict__ es4,
               const unsigned short* __restrict__ zembh, unsigned short* __restrict__ hb,
               float* __restrict__ bpart, int NW)
{
  const int lane = threadIdx.x & 63;
  const int wv   = threadIdx.x >> 6;
  const int w    = blockIdx.x * 4 + wv;
  float sreg[4][4] = {}, qreg[4][4] = {};
  if (w < NW) {
    const int n0 = wstart[w], n1 = wstart[w + 1];
    if (n0 < n1) {
      const int e0 = rowptr[n0], e1 = rowptr[n1];
      float4 acc[4] = {};
      int n = n0;
      int nb = rowptr[n + 1];
      auto flush = [&](int node) {
        #pragma unroll
        for (int l = 0; l < 4; ++l) {
          float4 v;
          v.x = fmaxf(acc[l].x, 0.f); v.y = fmaxf(acc[l].y, 0.f);
          v.z = fmaxf(acc[l].z, 0.f); v.w = fmaxf(acc[l].w, 0.f);
          ushort4 o;
          o.x = rne_bf16(v.x); o.y = rne_bf16(v.y); o.z = rne_bf16(v.z); o.w = rne_bf16(v.w);
          ((ushort4*)(hb + (size_t)node * HD4 + l * HD))[lane] = o;
          sreg[l][0] += v.x; sreg[l][1] += v.y; sreg[l][2] += v.z; sreg[l][3] += v.w;
          qreg[l][0] = fmaf(v.x, v.x, qreg[l][0]); qreg[l][1] = fmaf(v.y, v.y, qreg[l][1]);
          qreg[l][2] = fmaf(v.z, v.z, qreg[l][2]); qreg[l][3] = fmaf(v.w, v.w, qreg[l][3]);
          acc[l] = make_float4(0.f, 0.f, 0.f, 0.f);
        }
      };
      int sw_n = 0; float4 a_n = make_float4(0.f, 0.f, 0.f, 0.f);
      if (e0 < e1) { sw_n = swids[e0]; a_n = es4[e0]; }
      for (int e = e0; e < e1; ++e) {
        const int sw = sw_n;
        const float4 a = a_n;
        const ushort4* zb = (const ushort4*)(zembh + (size_t)sw * HD4) + lane;
        ushort4 z0 = zb[0], z1 = zb[64], z2 = zb[128], z3 = zb[192];
        if (e + 1 < e1) { sw_n = swids[e + 1]; a_n = es4[e + 1]; }
        while (e >= nb) { flush(n); ++n; nb = rowptr[n + 1]; }   // overlaps z latency
        fma4(acc[0], a.x, z0);
        fma4(acc[1], a.y, z1);
        fma4(acc[2], a.z, z2);
        fma4(acc[3], a.w, z3);
      }
      while (n < n1) { flush(n); ++n; }
    }
  }
  __shared__ float ls[4][64][4];
  __shared__ float lq[4][64][4];
  float* bp = bpart + (size_t)blockIdx.x * 2048;
  for (int l = 0; l < 4; ++l) {
    #pragma unroll
    for (int j = 0; j < 4; ++j) { ls[wv][lane][j] = sreg[l][j]; lq[wv][lane][j] = qreg[l][j]; }
    __syncthreads();
    if (wv == 0) {
      #pragma unroll
      for (int j = 0; j < 4; ++j) {
        float s4 = ls[0][lane][j] + ls[1][lane][j] + ls[2][lane][j] + ls[3][lane][j];
        float q4 = lq[0][lane][j] + lq[1][lane][j] + lq[2][lane][j] + lq[3][lane][j];
        bp[l * HD + lane * 4 + j] = s4;            // per-block partial, no atomics
        bp[1024 + l * HD + lane * 4 + j] = q4;
      }
    }
    __syncthreads();
  }
}

// stage-1 reduce: part2[c][h] = sum over blk in chunk c of bpart[blk][h]
__global__ void bn_reduce1(const float* __restrict__ bpart, float* __restrict__ part2, int nblk) {
  const int h = (blockIdx.x & 7) * 256 + threadIdx.x;
  const int c = blockIdx.x >> 3;
  const int b0 = c * RCHUNK;
  const int b1 = min(b0 + RCHUNK, nblk);
  float s = 0.f;
  for (int b = b0; b < b1; ++b) s += bpart[(size_t)b * 2048 + h];
  part2[(size_t)c * 2048 + h] = s;
}
// stage-2 reduce
__global__ void bn_reduce2(const float* __restrict__ part2, float* __restrict__ bsq, int nchunk) {
  const int h = blockIdx.x * 256 + threadIdx.x;
  float s = 0.f;
  for (int c = 0; c < nchunk; ++c) s += part2[(size_t)c * 2048 + h];
  bsq[h] = s;
}

// all 4 layers' BN coefficients
__global__ void bn_fin4(const float* __restrict__ bs, const float* __restrict__ bq,
                        const float* __restrict__ gamma, const float* __restrict__ beta,
                        float* __restrict__ sc, float* __restrict__ sh, float invN)
{
  int h = blockIdx.x * 256 + threadIdx.x;
  float mu  = bs[h] * invN;
  float var = fmaxf(bq[h] * invN - mu * mu, 0.f);
  float s = gamma[h] * rsqrtf(var + 1e-5f);
  sc[h] = s;
  sh[h] = fmaf(-mu, s, beta[h]);
}

// dual GRU cell (bf16 gate inputs): two independent parameter sets in one launch
struct CS {
  const unsigned short* gi; int gild;
  const unsigned short* gh; int ghld;
  const float* bih; const float* bhh;
  const float* hp; int hld;
  float* out; int outld;
  unsigned short* ob1; int ob1ld;
  unsigned short* ob2; int ob2ld;
};

__global__ __launch_bounds__(256)
void gru_cell2(CS A, CS B_, int Bn)
{
  int i = blockIdx.x * 256 + threadIdx.x;
  if (i >= 2 * Bn * HD) return;
  const bool second = i >= Bn * HD;
  const CS& S = second ? B_ : A;
  const int j = second ? i - Bn * HD : i;
  const int b = j >> 8, h = j & 255;
  const unsigned short* gr = S.gi + (size_t)b * S.gild;
  float ir  = b2f(gr[h])       + S.bih[h];
  float iz  = b2f(gr[HD + h])  + S.bih[HD + h];
  float in_ = b2f(gr[HD2 + h]) + S.bih[HD2 + h];
  float hrv = S.bhh[h], hzv = S.bhh[HD + h], hnv = S.bhh[HD2 + h];
  if (S.gh) {
    const unsigned short* gg = S.gh + (size_t)b * S.ghld;
    hrv += b2f(gg[h]); hzv += b2f(gg[HD + h]); hnv += b2f(gg[HD2 + h]);
  }
  float hp = S.hp ? S.hp[(size_t)b * S.hld + h] : 0.f;
  float rg = 1.f / (1.f + expf(-(ir + hrv)));
  float zg = 1.f / (1.f + expf(-(iz + hzv)));
  float n  = tanhf(fmaf(rg, hnv, in_));
  float hv = (1.f - zg) * n + zg * hp;
  S.out[(size_t)b * S.outld + h] = hv;
  unsigned short hb16 = rne_bf16(hv);
  if (S.ob1) S.ob1[(size_t)b * S.ob1ld + h] = hb16;
  if (S.ob2) S.ob2[(size_t)b * S.ob2ld + h] = hb16;
}

__global__ void readout_k(const float* __restrict__ y0, const float* __restrict__ hf1,
                          const float* __restrict__ hf2, float* __restrict__ out, int Bn)
{
  int i = blockIdx.x * 256 + threadIdx.x;
  if (i >= Bn * HD) return;
  int b = i >> 8, h = i & 255;
  out[i] = y0[(size_t)b * HD4 + HD2 + h] + y0[(size_t)b * HD4 + HD + h] + hf1[i] + hf2[i];
}

extern "C" void kernel_launch(void* const* d_in, const int* in_sizes, int n_in,
                              void* d_out, int out_size, void* d_ws, size_t ws_size,
                              hipStream_t stream)
{
  const int*   wid   = (const int*)d_in[0];
  const int*   src   = (const int*)d_in[1];
  const int*   dst   = (const int*)d_in[2];
  const int*   n2g   = (const int*)d_in[3];
  const float* emb   = (const float*)d_in[4];
  const float* gatW  = (const float*)d_in[5];
  const float* gatAs = (const float*)d_in[6];
  const float* gatAd = (const float*)d_in[7];
  const float* gatG  = (const float*)d_in[8];
  const float* gatB  = (const float*)d_in[9];
  const float* Wout  = (const float*)d_in[10];
  const float* bout  = (const float*)d_in[11];
  const float* Wih0  = (const float*)d_in[12];
  const float* Whh0  = (const float*)d_in[13];
  const float* bih0  = (const float*)d_in[14];
  const float* bhh0  = (const float*)d_in[15];
  const float* Wih1  = (const float*)d_in[16];
  const float* Whh1  = (const float*)d_in[17];
  const float* bih1  = (const float*)d_in[18];
  const float* bhh1  = (const float*)d_in[19];
  (void)n_in; (void)out_size; (void)ws_size;

  const int N = in_sizes[0];
  const int E = in_sizes[1];
  const int V = in_sizes[4] / HD;

  float* out_newh = (float*)d_out;
  float* out_read = out_newh + (size_t)N * HD;

  // ---- workspace carve-up (256B-aligned)
  char* cp  = (char*)d_ws;
  auto alloc = [&](size_t bytes) { char* r = cp; cp += (bytes + 255) & ~(size_t)255; return r; };
  float* zemb  = (float*)alloc((size_t)V * HD4 * 4);
  unsigned short* zembh = (unsigned short*)alloc((size_t)V * HD4 * 2);
  float* psv   = (float*)alloc(4 * (size_t)V * 4);
  float* pdv   = (float*)alloc(4 * (size_t)V * 4);
  unsigned short* meanb = (unsigned short*)alloc((size_t)2 * NB * HD * 2);
  unsigned short* gi0b = (unsigned short*)alloc((size_t)2 * NB * 1536 * 2);  // bf16 input gates
  float* y0    = (float*)alloc((size_t)NB * HD4 * 4);
  unsigned short* y0b = (unsigned short*)alloc((size_t)NB * HD4 * 2);
  float* htA   = (float*)alloc((size_t)NB * HD * 4);
  float* htB   = (float*)alloc((size_t)NB * HD * 4);
  float* hf1   = (float*)alloc((size_t)NB * HD * 4);
  float* hf2   = (float*)alloc((size_t)NB * HD * 4);
  float* bpart = (float*)alloc((size_t)NBLK * 2048 * 4);   // per-block BN partials (32 MB)
  float* part2 = (float*)alloc((size_t)NCHUNK * 2048 * 4); // stage-1 partials (1 MB)
  float* bnsum = (float*)alloc(2048 * 4);
  float* bnsq  = bnsum + 1024;
  float* bnsc  = (float*)alloc(1024 * 4);
  float* bnsh  = (float*)alloc(1024 * 4);
  unsigned short* Wp = (unsigned short*)alloc((size_t)HD * HD4 * 2);
  float* shiftv = (float*)alloc(HD * 4);
  unsigned short* Wih0b16 = (unsigned short*)alloc((size_t)2 * HD3 * HD * 2);
  unsigned short* Whh0b16 = (unsigned short*)alloc((size_t)2 * HD3 * HD * 2);
  unsigned short* Wih1b16 = (unsigned short*)alloc((size_t)2 * HD3 * HD2 * 2);
  unsigned short* Whh1b16 = (unsigned short*)alloc((size_t)2 * HD3 * HD * 2);
  int* deg     = (int*)alloc((size_t)N * 4);
  int* rowptr  = (int*)alloc((size_t)(N + 4) * 4);
  int* cursor  = (int*)alloc((size_t)N * 4);
  int* swids   = (int*)alloc((size_t)E * 4);
  int* dwids   = (int*)alloc((size_t)E * 4);
  float4* es4  = (float4*)alloc((size_t)E * 16);
  int* grow    = (int*)alloc((size_t)(NB + 4) * 4);
  int* wstart  = (int*)alloc((size_t)(NWAVES + 8) * 4);
  int* bsum    = (int*)alloc(256 * 4);
  unsigned short* habf = (unsigned short*)alloc((size_t)N * HD4 * 2);
  // GRU scratch aliases habf (dead after the big GEMM reads it)
  unsigned short* ghb  = habf;                                               // [2B,1536] bf16
  unsigned short* hcat = habf + (size_t)2 * NB * 1536;                        // [2B,256] bf16

  auto gemmb = [&](const unsigned short* A, int lda, const unsigned short* B, int ldb,
                   const float* sv, float* C, unsigned short* Cb, int ldc,
                   int M, int Nout, int K) {
    gemm2<<<dim3((unsigned)((M + 127) / 128), (unsigned)(Nout / 256)), 512, 0, stream>>>(
        A, lda, B, ldb, sv, C, Cb, ldc, M, K);
  };
  auto cell2 = [&](const CS& A, const CS& B_) {
    gru_cell2<<<(2 * NB * HD + 255) / 256, 256, 0, stream>>>(A, B_, NB);
  };

  // ---- CSR by destination + balanced strips + graph rowptr
  const int nsb = (N + SCB - 1) / SCB;
  hipMemsetAsync(deg, 0, (size_t)N * sizeof(int), stream);
  deg_hist<<<(E + 255) / 256, 256, 0, stream>>>(dst, deg, E);
  scan_bsum<<<nsb, 256, 0, stream>>>(deg, bsum, N);
  scan_small<<<1, 64, 0, stream>>>(bsum, nsb);
  scan_final<<<nsb, 256, 0, stream>>>(deg, bsum, rowptr, N, E);
  hipMemcpyAsync(cursor, rowptr, (size_t)N * sizeof(int), hipMemcpyDeviceToDevice, stream);
  scatter_edges<<<(E + 255) / 256, 256, 0, stream>>>(src, dst, wid, cursor, swids, dwids, E);
  balance_strips<<<(NWAVES + 256) / 256, 256, 0, stream>>>(rowptr, wstart, N, E, NWAVES);
  grow_fill<<<(N + 256) / 256, 256, 0, stream>>>(n2g, grow, N, NB);

  // zemb = emb @ [4 layers W]^T ; bf16 copy; attention scalars; edge scores; alphas
  {
    dim3 g((unsigned)((V + TS - 1) / TS), (unsigned)(HD4 / TS));
    gemm_tn<<<g, 256, 0, stream>>>(emb, HD, gatW, HD, zemb, HD4, V, HD);
  }
  f2b_kernel<<<(V * HD4 + 255) / 256, 256, 0, stream>>>(zemb, zembh, V * HD4);
  psv_kernel<<<dim3((V + 3) / 4, 4), 256, 0, stream>>>(zemb, gatAs, gatAd, psv, pdv, V);
  edge_score<<<(E + 255) / 256, 256, 0, stream>>>(swids, dwids, psv, pdv, es4, E, V);
  alpha_node<<<(N + 255) / 256, 256, 0, stream>>>(rowptr, es4, N);

  // GRU weights -> bf16 (one fused launch)
  {
    const int na = 2 * HD3 * HD, nb_ = 2 * HD3 * HD, nc = 2 * HD3 * HD2, nd = 2 * HD3 * HD;
    f2b4_kernel<<<(na + nb_ + nc + nd + 255) / 256, 256, 0, stream>>>(
        Wih0, Wih0b16, na, Whh0, Whh0b16, nb_, Wih1, Wih1b16, nc, Whh1, Whh1b16, nd);
  }

  // mean1 = seg_mean(emb[wid]) -> bf16
  seg_mean<<<NB, 256, 0, stream>>>(emb, wid, grow, meanb);

  // ---- balanced strip aggregation (4 layers, bf16 z, block-partial BN) + 2-stage reduce
  gat_strip<<<NBLK, 256, 0, stream>>>(rowptr, wstart, swids, es4, zembh, habf, bpart, NWAVES);
  bn_reduce1<<<NCHUNK * 8, 256, 0, stream>>>(bpart, part2, NBLK);
  bn_reduce2<<<8, 256, 0, stream>>>(part2, bnsum, NCHUNK);
  bn_fin4<<<4, 256, 0, stream>>>(bnsum, bnsq, gatG, gatB, bnsc, bnsh, 1.f / (float)N);
  fold_w<<<HD, 256, 0, stream>>>(Wout, HD4, bnsc, bnsh, bout, Wp, HD4, shiftv, HD4);
  gemmb(habf, HD4, Wp, HD4, shiftv, out_newh, nullptr, HD, N, HD, HD4);

  // mean2 = seg_mean(new_h) -> bf16
  seg_mean<<<NB, 256, 0, stream>>>(out_newh, nullptr, grow, meanb + (size_t)NB * HD);

  // ---- GRU (T=2, 2 layers, bidir). y0[b,c]: c = t*2H + dir*H + h
  gemmb(meanb, HD, Wih0b16, HD, nullptr, nullptr, gi0b, 1536, 2 * NB, 1536, HD);
  {
    CS A = {gi0b, 1536, nullptr, 0, bih0, bhh0, nullptr, 0,
            y0, HD4, y0b, HD4, hcat, HD};
    CS B = {gi0b + (size_t)NB * 1536 + HD3, 1536, nullptr, 0, bih0 + HD3, bhh0 + HD3, nullptr, 0,
            y0 + HD2 + HD, HD4, y0b + HD2 + HD, HD4, hcat + (size_t)NB * HD, HD};
    cell2(A, B);
  }
  gemmb(hcat, HD, Whh0b16, HD, nullptr, nullptr, ghb, 1536, 2 * NB, 1536, HD);
  {
    CS A = {gi0b + (size_t)NB * 1536, 1536, ghb, 1536, bih0, bhh0, y0, HD4,
            y0 + HD2, HD4, y0b + HD2, HD4, nullptr, 0};
    CS B = {gi0b + HD3, 1536, ghb + (size_t)NB * 1536 + HD3, 1536, bih0 + HD3, bhh0 + HD3,
            y0 + HD2 + HD, HD4, y0 + HD, HD4, y0b + HD, HD4, nullptr, 0};
    cell2(A, B);
  }
  gemmb(y0b, HD2, Wih1b16, HD2, nullptr, nullptr, gi0b, 1536, 2 * NB, 1536, HD2);
  {
    CS A = {gi0b, 3072, nullptr, 0, bih1, bhh1, nullptr, 0,
            htA, HD, nullptr, 0, hcat, HD};
    CS B = {gi0b + 1536 + HD3, 3072, nullptr, 0, bih1 + HD3, bhh1 + HD3, nullptr, 0,
            htB, HD, nullptr, 0, hcat + (size_t)NB * HD, HD};
    cell2(A, B);
  }
  gemmb(hcat, HD, Whh1b16, HD, nullptr, nullptr, ghb, 1536, 2 * NB, 1536, HD);
  {
    CS A = {gi0b + 1536, 3072, ghb, 1536, bih1, bhh1, htA, HD,
            hf1, HD, nullptr, 0, nullptr, 0};
    CS B = {gi0b + HD3, 3072, ghb + (size_t)NB * 1536 + HD3, 1536, bih1 + HD3, bhh1 + HD3,
            htB, HD, hf2, HD, nullptr, 0, nullptr, 0};
    cell2(A, B);
  }

  readout_k<<<(NB * HD + 255) / 256, 256, 0, stream>>>(y0, hf1, hf2, out_read, NB);
}

// Round 18
// 478.276 us; speedup vs baseline: 1.0430x; 1.0430x over previous
//
#include <hip/hip_runtime.h>
#include <hip/hip_bf16.h>

#define HD  256
#define HD2 512
#define HD3 768
#define HD4 1024
#define NB  4096   // number of graphs (B)
#define NWAVES 8192
#define NBLK (NWAVES / 4)
#define RCHUNK 32
#define NCHUNK (NBLK / RCHUNK)

static __device__ __forceinline__ float lrelu(float x) { return x >= 0.f ? x : 0.01f * x; }
static __device__ __forceinline__ unsigned short rne_bf16(float f) {
  unsigned u = __float_as_uint(f);
  u += 0x7FFF + ((u >> 16) & 1);
  return (unsigned short)(u >> 16);
}
static __device__ __forceinline__ float b2f(unsigned short u) {
  return __uint_as_float((unsigned)u << 16);
}
static __device__ __forceinline__ void fma4(float4& acc, float a, ushort4 z) {
  acc.x = fmaf(a, b2f(z.x), acc.x);
  acc.y = fmaf(a, b2f(z.y), acc.y);
  acc.z = fmaf(a, b2f(z.z), acc.z);
  acc.w = fmaf(a, b2f(z.w), acc.w);
}

typedef short v8s __attribute__((ext_vector_type(8)));
typedef float v4f __attribute__((ext_vector_type(4)));

#define GLD16(gp, lp) __builtin_amdgcn_global_load_lds( \
    (const __attribute__((address_space(1))) void*)(gp), \
    (__attribute__((address_space(3))) void*)(lp), 16, 0, 0)

// ---------------- bf16 MFMA GEMM, 512 thr / 8 waves (2x4), block tile 128x256, BK=64.
// (R14-verified best: single-buffer, 2 barriers/step, zero-conflict XOR swizzle.)
__global__ __launch_bounds__(512)
void gemm2(const unsigned short* __restrict__ A, int lda,
           const unsigned short* __restrict__ B, int ldb,
           const float* __restrict__ shiftv,
           float* __restrict__ C, unsigned short* __restrict__ Cb, int ldc,
           int M, int K)
{
  __shared__ unsigned short Asw[128 * 64];   // 16 KB
  __shared__ unsigned short Bsw[256 * 64];   // 32 KB
  const int tid = threadIdx.x;
  const int lane = tid & 63, w = tid >> 6;   // 8 waves
  const int bm = blockIdx.x * 128, bn = blockIdx.y * 256;
  const int wr = w >> 2, wc = w & 3;         // wave tile: rows wr*64, cols wc*64
  const int fr = lane & 15, fkseg = lane >> 4;
  v4f acc[4][4] = {};
  for (int k0 = 0; k0 < K; k0 += 64) {
    #pragma unroll
    for (int i = 0; i < 2; ++i) {
      const int s = i * 512 + w * 64 + lane;
      const int row = s >> 3;
      const int gk = (s & 7) ^ (row & 7);
      int gr = bm + row; gr = gr < M ? gr : M - 1;
      GLD16(A + (size_t)gr * lda + k0 + gk * 8, &Asw[(size_t)(i * 512 + w * 64) * 8]);
    }
    #pragma unroll
    for (int i = 0; i < 4; ++i) {
      const int s = i * 512 + w * 64 + lane;
      const int row = s >> 3;
      const int gk = (s & 7) ^ (row & 7);
      GLD16(B + (size_t)(bn + row) * ldb + k0 + gk * 8, &Bsw[(size_t)(i * 512 + w * 64) * 8]);
    }
    __syncthreads();
    #pragma unroll
    for (int kk = 0; kk < 2; ++kk) {
      v8s a[4], b[4];
      #pragma unroll
      for (int m = 0; m < 4; ++m) {
        const int r = wr * 64 + m * 16 + fr;
        const int ks = kk * 4 + fkseg;
        a[m] = *(const v8s*)&Asw[(size_t)(r * 8 + (ks ^ (r & 7))) * 8];
      }
      #pragma unroll
      for (int n = 0; n < 4; ++n) {
        const int r = wc * 64 + n * 16 + fr;
        const int ks = kk * 4 + fkseg;
        b[n] = *(const v8s*)&Bsw[(size_t)(r * 8 + (ks ^ (r & 7))) * 8];
      }
      #pragma unroll
      for (int m = 0; m < 4; ++m)
        #pragma unroll
        for (int n = 0; n < 4; ++n)
          acc[m][n] = __builtin_amdgcn_mfma_f32_16x16x32_bf16(a[m], b[n], acc[m][n], 0, 0, 0);
    }
    __syncthreads();
  }
  const int cr = (lane >> 4) * 4;  // C frag: row=(lane>>4)*4+r, col=lane&15 (m89-verified)
  const int cc = lane & 15;
  #pragma unroll
  for (int m = 0; m < 4; ++m) {
    #pragma unroll
    for (int r = 0; r < 4; ++r) {
      const int row = bm + wr * 64 + m * 16 + cr + r;
      if (row < M) {
        const int col = bn + wc * 64 + cc;
        #pragma unroll
        for (int n = 0; n < 4; ++n) {
          float v = acc[m][n][r];
          if (shiftv) v += shiftv[col + n * 16];
          if (Cb) Cb[(size_t)row * ldc + col + n * 16] = rne_bf16(v);
          else    C [(size_t)row * ldc + col + n * 16] = v;
        }
      }
    }
  }
}

// Wp[n,k] = bf16(Wout[n,k]*sc[k]);  shiftv[n] = bout[n] + sum_k sh[k]*Wout[n,k]
__global__ __launch_bounds__(256)
void fold_w(const float* __restrict__ Wout, int ldw,
            const float* __restrict__ sc, const float* __restrict__ sh,
            const float* __restrict__ bout,
            unsigned short* __restrict__ Wp, int ldp,
            float* __restrict__ shiftv, int K)
{
  const int n = blockIdx.x;
  const int t = threadIdx.x;
  float s = 0.f;
  for (int k = t; k < K; k += 256) {
    float wv = Wout[(size_t)n * ldw + k];
    s = fmaf(sh[k], wv, s);
    Wp[(size_t)n * ldp + k] = rne_bf16(wv * sc[k]);
  }
  __shared__ float red[256];
  red[t] = s; __syncthreads();
  for (int o = 128; o; o >>= 1) { if (t < o) red[t] += red[t + o]; __syncthreads(); }
  if (t == 0) shiftv[n] = red[0] + (bout ? bout[n] : 0.f);
}

// fused 4-buffer fp32->bf16 (GRU weights)
__global__ void f2b4_kernel(const float* __restrict__ a, unsigned short* __restrict__ da, int na,
                            const float* __restrict__ b, unsigned short* __restrict__ db, int nb_,
                            const float* __restrict__ c, unsigned short* __restrict__ dc, int nc,
                            const float* __restrict__ d, unsigned short* __restrict__ dd, int nd) {
  int i = blockIdx.x * 256 + threadIdx.x;
  if (i < na) { da[i] = rne_bf16(a[i]); return; }
  i -= na;
  if (i < nb_) { db[i] = rne_bf16(b[i]); return; }
  i -= nb_;
  if (i < nc) { dc[i] = rne_bf16(c[i]); return; }
  i -= nc;
  if (i < nd) dd[i] = rne_bf16(d[i]);
}

// ---------------- generic fp32 GEMM (zemb): writes fp32 C and optional bf16 Cb mirror
#define TS 64
#define KS 16
__global__ __launch_bounds__(256)
void gemm_tn(const float* __restrict__ A, int lda,
             const float* __restrict__ W, int ldw,
             float* __restrict__ C, unsigned short* __restrict__ Cb, int ldc,
             int M, int K)
{
  __shared__ float As[KS][TS + 1];
  __shared__ float Ws[KS][TS + 1];
  const int tid = threadIdx.x;
  const int bm = blockIdx.x * TS;
  const int bn = blockIdx.y * TS;
  const int r  = tid >> 2;
  const int kc = (tid & 3) << 2;
  const int tm = (tid >> 4) << 2;
  const int tn = (tid & 15) << 2;
  float acc[4][4] = {};
  for (int k0 = 0; k0 < K; k0 += KS) {
    float4 av = make_float4(0.f, 0.f, 0.f, 0.f);
    const int row = bm + r;
    if (row < M) av = *(const float4*)(A + (size_t)row * lda + k0 + kc);
    As[kc + 0][r] = av.x; As[kc + 1][r] = av.y; As[kc + 2][r] = av.z; As[kc + 3][r] = av.w;
    float4 wv = *(const float4*)(W + (size_t)(bn + r) * ldw + k0 + kc);
    Ws[kc + 0][r] = wv.x; Ws[kc + 1][r] = wv.y; Ws[kc + 2][r] = wv.z; Ws[kc + 3][r] = wv.w;
    __syncthreads();
    #pragma unroll
    for (int kk = 0; kk < KS; ++kk) {
      float a_[4], b_[4];
      #pragma unroll
      for (int i = 0; i < 4; ++i) a_[i] = As[kk][tm + i];
      #pragma unroll
      for (int j = 0; j < 4; ++j) b_[j] = Ws[kk][tn + j];
      #pragma unroll
      for (int i = 0; i < 4; ++i)
        #pragma unroll
        for (int j = 0; j < 4; ++j) acc[i][j] = fmaf(a_[i], b_[j], acc[i][j]);
    }
    __syncthreads();
  }
  #pragma unroll
  for (int i = 0; i < 4; ++i) {
    const int row = bm + tm + i;
    if (row < M) {
      *(float4*)(C + (size_t)row * ldc + bn + tn) =
          make_float4(acc[i][0], acc[i][1], acc[i][2], acc[i][3]);
      if (Cb) {
        ushort4 o;
        o.x = rne_bf16(acc[i][0]); o.y = rne_bf16(acc[i][1]);
        o.z = rne_bf16(acc[i][2]); o.w = rne_bf16(acc[i][3]);
        *(ushort4*)(Cb + (size_t)row * ldc + bn + tn) = o;
      }
    }
  }
}

// per-vocab attention scalars
__global__ __launch_bounds__(256)
void psv_kernel(const float* __restrict__ zemb, const float* __restrict__ as_,
                const float* __restrict__ ad_, float* __restrict__ psv,
                float* __restrict__ pdv, int V)
{
  int v = (int)((blockIdx.x * 256u + threadIdx.x) >> 6);
  int l = blockIdx.y;
  int lane = threadIdx.x & 63;
  if (v >= V) return;
  float4 zv = ((const float4*)(zemb + (size_t)v * HD4 + (size_t)l * HD))[lane];
  float4 a  = ((const float4*)(as_ + (size_t)l * HD))[lane];
  float4 b  = ((const float4*)(ad_ + (size_t)l * HD))[lane];
  float s = zv.x * a.x + zv.y * a.y + zv.z * a.z + zv.w * a.w;
  float d = zv.x * b.x + zv.y * b.y + zv.z * b.z + zv.w * b.w;
  #pragma unroll
  for (int o = 32; o; o >>= 1) { s += __shfl_down(s, o); d += __shfl_down(d, o); }
  if (lane == 0) { psv[(size_t)l * V + v] = s; pdv[(size_t)l * V + v] = d; }
}

// ---------------- CSR build (by dst) ----------------
__global__ void deg_hist(const int* __restrict__ dst, int* __restrict__ deg, int E) {
  int e = blockIdx.x * 256 + threadIdx.x;
  if (e < E) atomicAdd(&deg[dst[e]], 1);
}

#define SCB 1024
__global__ void scan_bsum(const int* __restrict__ deg, int* __restrict__ bsum, int N) {
  __shared__ int sh[256];
  int base = blockIdx.x * SCB;
  int t = threadIdx.x;
  int s = 0;
  for (int i = t; i < SCB; i += 256) { int idx = base + i; s += (idx < N) ? deg[idx] : 0; }
  sh[t] = s; __syncthreads();
  for (int o = 128; o; o >>= 1) { if (t < o) sh[t] += sh[t + o]; __syncthreads(); }
  if (t == 0) bsum[blockIdx.x] = sh[0];
}
__global__ void scan_small(int* __restrict__ bsum, int nb) {
  if (threadIdx.x == 0) {
    int acc = 0;
    for (int i = 0; i < nb; ++i) { int v = bsum[i]; bsum[i] = acc; acc += v; }
  }
}
__global__ void scan_final(const int* __restrict__ deg, const int* __restrict__ bsum,
                           int* __restrict__ rowptr, int N, int E) {
  __shared__ int sh[256];
  int base = blockIdx.x * SCB;
  int t = threadIdx.x;
  int idx0 = base + t * 4;
  int v[4]; int s = 0;
  #pragma unroll
  for (int j = 0; j < 4; ++j) { int idx = idx0 + j; v[j] = (idx < N) ? deg[idx] : 0; s += v[j]; }
  sh[t] = s; __syncthreads();
  for (int o = 1; o < 256; o <<= 1) {
    int x = (t >= o) ? sh[t - o] : 0;
    __syncthreads();
    sh[t] += x;
    __syncthreads();
  }
  int off = bsum[blockIdx.x] + ((t == 0) ? 0 : sh[t - 1]);
  #pragma unroll
  for (int j = 0; j < 4; ++j) {
    int idx = idx0 + j;
    if (idx < N) rowptr[idx] = off;
    off += v[j];
  }
  if (idx0 <= N - 1 && N - 1 < idx0 + 4) rowptr[N] = E;
}
__global__ void scatter_edges(const int* __restrict__ src, const int* __restrict__ dst,
                              const int* __restrict__ wid, int* __restrict__ cursor,
                              int* __restrict__ swids, int* __restrict__ dwids, int E) {
  int e = blockIdx.x * 256 + threadIdx.x;
  if (e >= E) return;
  int pos = atomicAdd(&cursor[dst[e]], 1);
  swids[pos] = wid[src[e]];
  dwids[pos] = wid[dst[e]];
}

// edge-balanced strip boundaries
__global__ void balance_strips(const int* __restrict__ rowptr, int* __restrict__ wstart,
                               int N, int E, int NW) {
  int w = blockIdx.x * 256 + threadIdx.x;
  if (w > NW) return;
  if (w == 0)  { wstart[0] = 0; return; }
  if (w == NW) { wstart[NW] = N; return; }
  long long target = (long long)E * w / NW;
  int lo = 0, hi = N;
  while (lo < hi) {
    int mid = (lo + hi + 1) >> 1;
    if ((long long)rowptr[mid] <= target) lo = mid; else hi = mid - 1;
  }
  wstart[w] = lo;
}

// graph rowptr from sorted n2g
__global__ void grow_fill(const int* __restrict__ n2g, int* __restrict__ grow, int N, int B) {
  int n = blockIdx.x * 256 + threadIdx.x;
  if (n > N) return;
  int prev = (n == 0) ? -1 : n2g[n - 1];
  int cur  = (n == N) ? B  : n2g[n];
  for (int g = prev + 1; g <= cur && g <= B; ++g) grow[g] = n;
}

// block-per-graph mean (sorted segments, no atomics), bf16 output
__global__ __launch_bounds__(256)
void seg_mean(const float* __restrict__ X, const int* __restrict__ gather,
              const int* __restrict__ grow, unsigned short* __restrict__ outb)
{
  int g = blockIdx.x, h = threadIdx.x;
  int n0 = grow[g], n1 = grow[g + 1];
  float s = 0.f;
  for (int n = n0; n < n1; ++n) {
    int row = gather ? gather[n] : n;
    s += X[(size_t)row * HD + h];
  }
  outb[(size_t)g * HD + h] = rne_bf16(s / fmaxf((float)(n1 - n0), 1.f));
}

// fused per-node softmax: compute scores inline (L1-resident psv/pdv tables), write alphas
__global__ __launch_bounds__(256)
void alpha_node(const int* __restrict__ rowptr, const int* __restrict__ swids,
                const int* __restrict__ dwids, const float* __restrict__ psv,
                const float* __restrict__ pdv, float4* __restrict__ es4, int N, int V) {
  int n = blockIdx.x * 256 + threadIdx.x;
  if (n >= N) return;
  int b0 = rowptr[n], b1 = rowptr[n + 1];
  if (b0 == b1) return;
  const int dw = dwids[b0];
  const float pd0 = pdv[dw], pd1 = pdv[V + dw], pd2 = pdv[2 * V + dw], pd3 = pdv[3 * V + dw];
  float4 m = make_float4(-INFINITY, -INFINITY, -INFINITY, -INFINITY);
  for (int i = b0; i < b1; ++i) {
    const int sw = swids[i];
    m.x = fmaxf(m.x, lrelu(psv[sw] + pd0));
    m.y = fmaxf(m.y, lrelu(psv[V + sw] + pd1));
    m.z = fmaxf(m.z, lrelu(psv[2 * V + sw] + pd2));
    m.w = fmaxf(m.w, lrelu(psv[3 * V + sw] + pd3));
  }
  float4 s = make_float4(0.f, 0.f, 0.f, 0.f);
  for (int i = b0; i < b1; ++i) {
    const int sw = swids[i];
    float4 e;
    e.x = expf(lrelu(psv[sw] + pd0) - m.x);
    e.y = expf(lrelu(psv[V + sw] + pd1) - m.y);
    e.z = expf(lrelu(psv[2 * V + sw] + pd2) - m.z);
    e.w = expf(lrelu(psv[3 * V + sw] + pd3) - m.w);
    s.x += e.x; s.y += e.y; s.z += e.z; s.w += e.w;
    es4[i] = e;
  }
  float4 inv;
  inv.x = 1.f / (s.x == 0.f ? 1.f : s.x);
  inv.y = 1.f / (s.y == 0.f ? 1.f : s.y);
  inv.z = 1.f / (s.z == 0.f ? 1.f : s.z);
  inv.w = 1.f / (s.w == 0.f ? 1.f : s.w);
  for (int i = b0; i < b1; ++i) {
    float4 e = es4[i];
    e.x *= inv.x; e.y *= inv.y; e.z *= inv.z; e.w *= inv.w;
    es4[i] = e;
  }
}

// ---------------- edge-balanced strip aggregation; per-block BN partials (NO global atomics)
__global__ __launch_bounds__(256)
void gat_strip(const int* __restrict__ rowptr, const int* __restrict__ wstart,
               const int* __restrict__ swids, const float4* __restrict__ es4,
               const unsigned short* __restrict__ zembh, unsigned short* __restrict__ hb,
               float* __restrict__ bpart, int NW)
{
  const int lane = threadIdx.x & 63;
  const int wv   = threadIdx.x >> 6;
  const int w    = blockIdx.x * 4 + wv;
  float sreg[4][4] = {}, qreg[4][4] = {};
  if (w < NW) {
    const int n0 = wstart[w], n1 = wstart[w + 1];
    if (n0 < n1) {
      const int e0 = rowptr[n0], e1 = rowptr[n1];
      float4 acc[4] = {};
      int n = n0;
      int nb = rowptr[n + 1];
      auto flush = [&](int node) {
        #pragma unroll
        for (int l = 0; l < 4; ++l) {
          float4 v;
          v.x = fmaxf(acc[l].x, 0.f); v.y = fmaxf(acc[l].y, 0.f);
          v.z = fmaxf(acc[l].z, 0.f); v.w = fmaxf(acc[l].w, 0.f);
          ushort4 o;
          o.x = rne_bf16(v.x); o.y = rne_bf16(v.y); o.z = rne_bf16(v.z); o.w = rne_bf16(v.w);
          ((ushort4*)(hb + (size_t)node * HD4 + l * HD))[lane] = o;
          sreg[l][0] += v.x; sreg[l][1] += v.y; sreg[l][2] += v.z; sreg[l][3] += v.w;
          qreg[l][0] = fmaf(v.x, v.x, qreg[l][0]); qreg[l][1] = fmaf(v.y, v.y, qreg[l][1]);
          qreg[l][2] = fmaf(v.z, v.z, qreg[l][2]); qreg[l][3] = fmaf(v.w, v.w, qreg[l][3]);
          acc[l] = make_float4(0.f, 0.f, 0.f, 0.f);
        }
      };
      int sw_n = 0; float4 a_n = make_float4(0.f, 0.f, 0.f, 0.f);
      if (e0 < e1) { sw_n = swids[e0]; a_n = es4[e0]; }
      for (int e = e0; e < e1; ++e) {
        const int sw = sw_n;
        const float4 a = a_n;
        const ushort4* zb = (const ushort4*)(zembh + (size_t)sw * HD4) + lane;
        ushort4 z0 = zb[0], z1 = zb[64], z2 = zb[128], z3 = zb[192];
        if (e + 1 < e1) { sw_n = swids[e + 1]; a_n = es4[e + 1]; }
        while (e >= nb) { flush(n); ++n; nb = rowptr[n + 1]; }   // overlaps z latency
        fma4(acc[0], a.x, z0);
        fma4(acc[1], a.y, z1);
        fma4(acc[2], a.z, z2);
        fma4(acc[3], a.w, z3);
      }
      while (n < n1) { flush(n); ++n; }
    }
  }
  __shared__ float ls[4][64][4];
  __shared__ float lq[4][64][4];
  float* bp = bpart + (size_t)blockIdx.x * 2048;
  for (int l = 0; l < 4; ++l) {
    #pragma unroll
    for (int j = 0; j < 4; ++j) { ls[wv][lane][j] = sreg[l][j]; lq[wv][lane][j] = qreg[l][j]; }
    __syncthreads();
    if (wv == 0) {
      #pragma unroll
      for (int j = 0; j < 4; ++j) {
        float s4 = ls[0][lane][j] + ls[1][lane][j] + ls[2][lane][j] + ls[3][lane][j];
        float q4 = lq[0][lane][j] + lq[1][lane][j] + lq[2][lane][j] + lq[3][lane][j];
        bp[l * HD + lane * 4 + j] = s4;            // per-block partial, no atomics
        bp[1024 + l * HD + lane * 4 + j] = q4;
      }
    }
    __syncthreads();
  }
}

// stage-1 reduce: part2[c][h] = sum over blk in chunk c of bpart[blk][h]
__global__ void bn_reduce1(const float* __restrict__ bpart, float* __restrict__ part2, int nblk) {
  const int h = (blockIdx.x & 7) * 256 + threadIdx.x;
  const int c = blockIdx.x >> 3;
  const int b0 = c * RCHUNK;
  const int b1 = min(b0 + RCHUNK, nblk);
  float s = 0.f;
  for (int b = b0; b < b1; ++b) s += bpart[(size_t)b * 2048 + h];
  part2[(size_t)c * 2048 + h] = s;
}
// stage-2 reduce
__global__ void bn_reduce2(const float* __restrict__ part2, float* __restrict__ bsq, int nchunk) {
  const int h = blockIdx.x * 256 + threadIdx.x;
  float s = 0.f;
  for (int c = 0; c < nchunk; ++c) s += part2[(size_t)c * 2048 + h];
  bsq[h] = s;
}

// all 4 layers' BN coefficients
__global__ void bn_fin4(const float* __restrict__ bs, const float* __restrict__ bq,
                        const float* __restrict__ gamma, const float* __restrict__ beta,
                        float* __restrict__ sc, float* __restrict__ sh, float invN)
{
  int h = blockIdx.x * 256 + threadIdx.x;
  float mu  = bs[h] * invN;
  float var = fmaxf(bq[h] * invN - mu * mu, 0.f);
  float s = gamma[h] * rsqrtf(var + 1e-5f);
  sc[h] = s;
  sh[h] = fmaf(-mu, s, beta[h]);
}

// dual GRU cell (bf16 gate inputs): two independent parameter sets in one launch
struct CS {
  const unsigned short* gi; int gild;
  const unsigned short* gh; int ghld;
  const float* bih; const float* bhh;
  const float* hp; int hld;
  float* out; int outld;
  unsigned short* ob1; int ob1ld;
  unsigned short* ob2; int ob2ld;
};

__global__ __launch_bounds__(256)
void gru_cell2(CS A, CS B_, int Bn)
{
  int i = blockIdx.x * 256 + threadIdx.x;
  if (i >= 2 * Bn * HD) return;
  const bool second = i >= Bn * HD;
  const CS& S = second ? B_ : A;
  const int j = second ? i - Bn * HD : i;
  const int b = j >> 8, h = j & 255;
  const unsigned short* gr = S.gi + (size_t)b * S.gild;
  float ir  = b2f(gr[h])       + S.bih[h];
  float iz  = b2f(gr[HD + h])  + S.bih[HD + h];
  float in_ = b2f(gr[HD2 + h]) + S.bih[HD2 + h];
  float hrv = S.bhh[h], hzv = S.bhh[HD + h], hnv = S.bhh[HD2 + h];
  if (S.gh) {
    const unsigned short* gg = S.gh + (size_t)b * S.ghld;
    hrv += b2f(gg[h]); hzv += b2f(gg[HD + h]); hnv += b2f(gg[HD2 + h]);
  }
  float hp = S.hp ? S.hp[(size_t)b * S.hld + h] : 0.f;
  float rg = 1.f / (1.f + expf(-(ir + hrv)));
  float zg = 1.f / (1.f + expf(-(iz + hzv)));
  float n  = tanhf(fmaf(rg, hnv, in_));
  float hv = (1.f - zg) * n + zg * hp;
  S.out[(size_t)b * S.outld + h] = hv;
  unsigned short hb16 = rne_bf16(hv);
  if (S.ob1) S.ob1[(size_t)b * S.ob1ld + h] = hb16;
  if (S.ob2) S.ob2[(size_t)b * S.ob2ld + h] = hb16;
}

__global__ void readout_k(const float* __restrict__ y0, const float* __restrict__ hf1,
                          const float* __restrict__ hf2, float* __restrict__ out, int Bn)
{
  int i = blockIdx.x * 256 + threadIdx.x;
  if (i >= Bn * HD) return;
  int b = i >> 8, h = i & 255;
  out[i] = y0[(size_t)b * HD4 + HD2 + h] + y0[(size_t)b * HD4 + HD + h] + hf1[i] + hf2[i];
}

extern "C" void kernel_launch(void* const* d_in, const int* in_sizes, int n_in,
                              void* d_out, int out_size, void* d_ws, size_t ws_size,
                              hipStream_t stream)
{
  const int*   wid   = (const int*)d_in[0];
  const int*   src   = (const int*)d_in[1];
  const int*   dst   = (const int*)d_in[2];
  const int*   n2g   = (const int*)d_in[3];
  const float* emb   = (const float*)d_in[4];
  const float* gatW  = (const float*)d_in[5];
  const float* gatAs = (const float*)d_in[6];
  const float* gatAd = (const float*)d_in[7];
  const float* gatG  = (const float*)d_in[8];
  const float* gatB  = (const float*)d_in[9];
  const float* Wout  = (const float*)d_in[10];
  const float* bout  = (const float*)d_in[11];
  const float* Wih0  = (const float*)d_in[12];
  const float* Whh0  = (const float*)d_in[13];
  const float* bih0  = (const float*)d_in[14];
  const float* bhh0  = (const float*)d_in[15];
  const float* Wih1  = (const float*)d_in[16];
  const float* Whh1  = (const float*)d_in[17];
  const float* bih1  = (const float*)d_in[18];
  const float* bhh1  = (const float*)d_in[19];
  (void)n_in; (void)out_size; (void)ws_size;

  const int N = in_sizes[0];
  const int E = in_sizes[1];
  const int V = in_sizes[4] / HD;

  float* out_newh = (float*)d_out;
  float* out_read = out_newh + (size_t)N * HD;

  // ---- workspace carve-up (256B-aligned)
  char* cp  = (char*)d_ws;
  auto alloc = [&](size_t bytes) { char* r = cp; cp += (bytes + 255) & ~(size_t)255; return r; };
  float* zemb  = (float*)alloc((size_t)V * HD4 * 4);
  unsigned short* zembh = (unsigned short*)alloc((size_t)V * HD4 * 2);
  float* psv   = (float*)alloc(4 * (size_t)V * 4);
  float* pdv   = (float*)alloc(4 * (size_t)V * 4);
  unsigned short* meanb = (unsigned short*)alloc((size_t)2 * NB * HD * 2);
  unsigned short* gi0b = (unsigned short*)alloc((size_t)2 * NB * 1536 * 2);  // bf16 input gates
  float* y0    = (float*)alloc((size_t)NB * HD4 * 4);
  unsigned short* y0b = (unsigned short*)alloc((size_t)NB * HD4 * 2);
  float* htA   = (float*)alloc((size_t)NB * HD * 4);
  float* htB   = (float*)alloc((size_t)NB * HD * 4);
  float* hf1   = (float*)alloc((size_t)NB * HD * 4);
  float* hf2   = (float*)alloc((size_t)NB * HD * 4);
  float* bpart = (float*)alloc((size_t)NBLK * 2048 * 4);   // per-block BN partials (16 MB)
  float* part2 = (float*)alloc((size_t)NCHUNK * 2048 * 4); // stage-1 partials (512 KB)
  float* bnsum = (float*)alloc(2048 * 4);
  float* bnsq  = bnsum + 1024;
  float* bnsc  = (float*)alloc(1024 * 4);
  float* bnsh  = (float*)alloc(1024 * 4);
  unsigned short* Wp = (unsigned short*)alloc((size_t)HD * HD4 * 2);
  float* shiftv = (float*)alloc(HD * 4);
  unsigned short* Wih0b16 = (unsigned short*)alloc((size_t)2 * HD3 * HD * 2);
  unsigned short* Whh0b16 = (unsigned short*)alloc((size_t)2 * HD3 * HD * 2);
  unsigned short* Wih1b16 = (unsigned short*)alloc((size_t)2 * HD3 * HD2 * 2);
  unsigned short* Whh1b16 = (unsigned short*)alloc((size_t)2 * HD3 * HD * 2);
  int* deg     = (int*)alloc((size_t)N * 4);
  int* rowptr  = (int*)alloc((size_t)(N + 4) * 4);
  int* cursor  = (int*)alloc((size_t)N * 4);
  int* swids   = (int*)alloc((size_t)E * 4);
  int* dwids   = (int*)alloc((size_t)E * 4);
  float4* es4  = (float4*)alloc((size_t)E * 16);
  int* grow    = (int*)alloc((size_t)(NB + 4) * 4);
  int* wstart  = (int*)alloc((size_t)(NWAVES + 8) * 4);
  int* bsum    = (int*)alloc(256 * 4);
  unsigned short* habf = (unsigned short*)alloc((size_t)N * HD4 * 2);
  // GRU scratch aliases habf (dead after the big GEMM reads it)
  unsigned short* ghb  = habf;                                               // [2B,1536] bf16
  unsigned short* hcat = habf + (size_t)2 * NB * 1536;                        // [2B,256] bf16

  auto gemmb = [&](const unsigned short* A, int lda, const unsigned short* B, int ldb,
                   const float* sv, float* C, unsigned short* Cb, int ldc,
                   int M, int Nout, int K) {
    gemm2<<<dim3((unsigned)((M + 127) / 128), (unsigned)(Nout / 256)), 512, 0, stream>>>(
        A, lda, B, ldb, sv, C, Cb, ldc, M, K);
  };
  auto cell2 = [&](const CS& A, const CS& B_) {
    gru_cell2<<<(2 * NB * HD + 255) / 256, 256, 0, stream>>>(A, B_, NB);
  };

  // ---- CSR by destination + balanced strips + graph rowptr
  const int nsb = (N + SCB - 1) / SCB;
  hipMemsetAsync(deg, 0, (size_t)N * sizeof(int), stream);
  deg_hist<<<(E + 255) / 256, 256, 0, stream>>>(dst, deg, E);
  scan_bsum<<<nsb, 256, 0, stream>>>(deg, bsum, N);
  scan_small<<<1, 64, 0, stream>>>(bsum, nsb);
  scan_final<<<nsb, 256, 0, stream>>>(deg, bsum, rowptr, N, E);
  hipMemcpyAsync(cursor, rowptr, (size_t)N * sizeof(int), hipMemcpyDeviceToDevice, stream);
  scatter_edges<<<(E + 255) / 256, 256, 0, stream>>>(src, dst, wid, cursor, swids, dwids, E);
  balance_strips<<<(NWAVES + 256) / 256, 256, 0, stream>>>(rowptr, wstart, N, E, NWAVES);
  grow_fill<<<(N + 256) / 256, 256, 0, stream>>>(n2g, grow, N, NB);

  // zemb = emb @ [4 layers W]^T (fp32 + bf16 mirror); attention scalars; fused alphas
  {
    dim3 g((unsigned)((V + TS - 1) / TS), (unsigned)(HD4 / TS));
    gemm_tn<<<g, 256, 0, stream>>>(emb, HD, gatW, HD, zemb, zembh, HD4, V, HD);
  }
  psv_kernel<<<dim3((V + 3) / 4, 4), 256, 0, stream>>>(zemb, gatAs, gatAd, psv, pdv, V);
  alpha_node<<<(N + 255) / 256, 256, 0, stream>>>(rowptr, swids, dwids, psv, pdv, es4, N, V);

  // GRU weights -> bf16 (one fused launch)
  {
    const int na = 2 * HD3 * HD, nb_ = 2 * HD3 * HD, nc = 2 * HD3 * HD2, nd = 2 * HD3 * HD;
    f2b4_kernel<<<(na + nb_ + nc + nd + 255) / 256, 256, 0, stream>>>(
        Wih0, Wih0b16, na, Whh0, Whh0b16, nb_, Wih1, Wih1b16, nc, Whh1, Whh1b16, nd);
  }

  // mean1 = seg_mean(emb[wid]) -> bf16
  seg_mean<<<NB, 256, 0, stream>>>(emb, wid, grow, meanb);

  // ---- balanced strip aggregation (4 layers, bf16 z, block-partial BN) + 2-stage reduce
  gat_strip<<<NBLK, 256, 0, stream>>>(rowptr, wstart, swids, es4, zembh, habf, bpart, NWAVES);
  bn_reduce1<<<NCHUNK * 8, 256, 0, stream>>>(bpart, part2, NBLK);
  bn_reduce2<<<8, 256, 0, stream>>>(part2, bnsum, NCHUNK);
  bn_fin4<<<4, 256, 0, stream>>>(bnsum, bnsq, gatG, gatB, bnsc, bnsh, 1.f / (float)N);
  fold_w<<<HD, 256, 0, stream>>>(Wout, HD4, bnsc, bnsh, bout, Wp, HD4, shiftv, HD4);
  gemmb(habf, HD4, Wp, HD4, shiftv, out_newh, nullptr, HD, N, HD, HD4);

  // mean2 = seg_mean(new_h) -> bf16
  seg_mean<<<NB, 256, 0, stream>>>(out_newh, nullptr, grow, meanb + (size_t)NB * HD);

  // ---- GRU (T=2, 2 layers, bidir). y0[b,c]: c = t*2H + dir*H + h
  gemmb(meanb, HD, Wih0b16, HD, nullptr, nullptr, gi0b, 1536, 2 * NB, 1536, HD);
  {
    CS A = {gi0b, 1536, nullptr, 0, bih0, bhh0, nullptr, 0,
            y0, HD4, y0b, HD4, hcat, HD};
    CS B = {gi0b + (size_t)NB * 1536 + HD3, 1536, nullptr, 0, bih0 + HD3, bhh0 + HD3, nullptr, 0,
            y0 + HD2 + HD, HD4, y0b + HD2 + HD, HD4, hcat + (size_t)NB * HD, HD};
    cell2(A, B);
  }
  gemmb(hcat, HD, Whh0b16, HD, nullptr, nullptr, ghb, 1536, 2 * NB, 1536, HD);
  {
    CS A = {gi0b + (size_t)NB * 1536, 1536, ghb, 1536, bih0, bhh0, y0, HD4,
            y0 + HD2, HD4, y0b + HD2, HD4, nullptr, 0};
    CS B = {gi0b + HD3, 1536, ghb + (size_t)NB * 1536 + HD3, 1536, bih0 + HD3, bhh0 + HD3,
            y0 + HD2 + HD, HD4, y0 + HD, HD4, y0b + HD, HD4, nullptr, 0};
    cell2(A, B);
  }
  gemmb(y0b, HD2, Wih1b16, HD2, nullptr, nullptr, gi0b, 1536, 2 * NB, 1536, HD2);
  {
    CS A = {gi0b, 3072, nullptr, 0, bih1, bhh1, nullptr, 0,
            htA, HD, nullptr, 0, hcat, HD};
    CS B = {gi0b + 1536 + HD3, 3072, nullptr, 0, bih1 + HD3, bhh1 + HD3, nullptr, 0,
            htB, HD, nullptr, 0, hcat + (size_t)NB * HD, HD};
    cell2(A, B);
  }
  gemmb(hcat, HD, Whh1b16, HD, nullptr, nullptr, ghb, 1536, 2 * NB, 1536, HD);
  {
    CS A = {gi0b + 1536, 3072, ghb, 1536, bih1, bhh1, htA, HD,
            hf1, HD, nullptr, 0, nullptr, 0};
    CS B = {gi0b + HD3, 3072, ghb + (size_t)NB * 1536 + HD3, 1536, bih1 + HD3, bhh1 + HD3,
            htB, HD, hf2, HD, nullptr, 0, nullptr, 0};
    cell2(A, B);
  }

  readout_k<<<(NB * HD + 255) / 256, 256, 0, stream>>>(y0, hf1, hf2, out_read, NB);
}